// Round 1
// baseline (6342.337 us; speedup 1.0000x reference)
//
#include <hip/hip_runtime.h>

#define Bn 32
#define Cn 64
#define Hn 64
#define Wn 64
#define On 128
#define HP 62
#define WP 62
#define CKn 576
#define Ln (HP*WP)          // 3844
#define NPOS (Bn*Ln)        // 123008
#define NROWS (Bn*HP)       // 1984
#define Y_ELEMS (Bn*On*Ln)  // 15745024

// ws layout (floats):
// wn   : [0,      73728)
// S1   : [73728,  73856)
// S2   : [73856,  73984)
// G    : [73984,  147712)
// m    : [147712, 270720)
// invd : [270720, 393728)

__global__ __launch_bounds__(256) void k_norm(const float* __restrict__ w, float* __restrict__ wn,
                                              float* __restrict__ S1, float* __restrict__ S2,
                                              float* __restrict__ G){
  int o = blockIdx.x; int t = threadIdx.x;
  for (int k = t; k < CKn; k += 256) G[o*CKn + k] = 0.f;
  if (t == 0){ S1[o] = 0.f; S2[o] = 0.f; }
  float s = 0.f;
  for (int k = t; k < CKn; k += 256){ float v = w[o*CKn + k]; s += v*v; }
  #pragma unroll
  for (int off = 32; off; off >>= 1) s += __shfl_down(s, off);
  __shared__ float red[4]; __shared__ float sh_inv;
  if ((t & 63) == 0) red[t >> 6] = s;
  __syncthreads();
  if (t == 0){
    float tot = red[0] + red[1] + red[2] + red[3];
    float nrm = sqrtf(tot);
    sh_inv = (nrm == 0.f) ? 1.f : 1.f/nrm;
  }
  __syncthreads();
  float inv = sh_inv;
  for (int k = t; k < CKn; k += 256) wn[o*CKn + k] = w[o*CKn + k]*inv;
}

// conv: block = 256 thr: 16 rows x 16 j-groups (4 outputs each). grid (B*O, 4)
__global__ __launch_bounds__(256) void k_conv(const float* __restrict__ x, const float* __restrict__ wn,
                                              const float* __restrict__ bias, float* __restrict__ y){
  int bo = blockIdx.x;
  int b = bo >> 7, o = bo & 127;
  int t = threadIdx.x;
  int jg = t & 15;
  int ir = t >> 4;
  int i = blockIdx.y*16 + ir;
  int j0 = jg*4;
  int i_ld = i < 62 ? i : 61;
  int c2 = (j0 + 4 <= 60) ? (j0 + 4) : 56;   // clamp keeps load in-bounds; lanes using it are masked
  const float* xb_base = x + (size_t)b*Cn*Hn*Wn;
  const float* wrow = wn + o*CKn;
  float acc0=0.f, acc1=0.f, acc2=0.f, acc3=0.f;
  for (int c = 0; c < Cn; c++){
    const float* xc = xb_base + (size_t)c*Hn*Wn + (size_t)i_ld*Wn;
    #pragma unroll
    for (int kh = 0; kh < 3; kh++){
      const float* xr = xc + kh*Wn;
      float4 a  = *(const float4*)(xr + j0);
      float4 bq = *(const float4*)(xr + c2);
      float w0 = wrow[c*9 + kh*3 + 0];
      float w1 = wrow[c*9 + kh*3 + 1];
      float w2 = wrow[c*9 + kh*3 + 2];
      acc0 += w0*a.x + w1*a.y + w2*a.z;
      acc1 += w0*a.y + w1*a.z + w2*a.w;
      acc2 += w0*a.z + w1*a.w + w2*bq.x;
      acc3 += w0*a.w + w1*bq.x + w2*bq.y;
    }
  }
  if (i < 62){
    float bv = bias[o];
    float* yp = y + (((size_t)b*On + o)*HP + i)*WP;
    yp[j0+0] = acc0 + bv;
    yp[j0+1] = acc1 + bv;
    if (j0+2 < 62) yp[j0+2] = acc2 + bv;
    if (j0+3 < 62) yp[j0+3] = acc3 + bv;
  }
}

// softmax stats: block = 4 rows x 64 lanes, grid (B, 16)
__global__ __launch_bounds__(256) void k_soft(const float* __restrict__ y, float* __restrict__ mbuf,
                                              float* __restrict__ invdbuf, float* __restrict__ S1,
                                              float* __restrict__ S2){
  __shared__ float s1loc[128], s2loc[128];
  int t = threadIdx.x;
  if (t < 128){ s1loc[t] = 0.f; s2loc[t] = 0.f; }
  __syncthreads();
  int b = blockIdx.x;
  int i = blockIdx.y*4 + (t >> 6);
  int j = t & 63;
  bool act = (i < 62) && (j < 62);
  const float* yp = y + (((size_t)b*On)*HP + (i < 62 ? i : 0))*WP + j;
  float mx = -3.0e38f;
  if (act){
    for (int o = 0; o < On; o++) mx = fmaxf(mx, yp[(size_t)o*Ln]);
  }
  float den = 0.f;
  if (act){
    for (int o = 0; o < On; o++) den += __expf(yp[(size_t)o*Ln] - mx);
  }
  float inv = act ? 1.f/den : 0.f;
  if (act){
    int pos = (b*HP + i)*WP + j;
    mbuf[pos] = mx; invdbuf[pos] = inv;
  }
  for (int o = 0; o < On; o++){
    float r = act ? __expf(yp[(size_t)o*Ln] - mx)*inv : 0.f;
    float s1v = r, s2v = r*r;
    #pragma unroll
    for (int off = 32; off; off >>= 1){ s1v += __shfl_down(s1v, off); s2v += __shfl_down(s2v, off); }
    if (j == 0 && (t >> 6) >= 0){
      if ((t & 63) == 0){ atomicAdd(&s1loc[o], s1v); atomicAdd(&s2loc[o], s2v); }
    }
  }
  __syncthreads();
  if (t < 128){ atomicAdd(&S1[t], s1loc[t]); atomicAdd(&S2[t], s2loc[t]); }
}

// delta partial: block = 1 wave, lane = channel c, 9 taps per lane. grid (O, NROWS/16)
__global__ __launch_bounds__(64) void k_delta(const float* __restrict__ x, const float* __restrict__ y,
                                              const float* __restrict__ mbuf, const float* __restrict__ invdbuf,
                                              float* __restrict__ G){
  __shared__ __align__(16) float pl[64];
  int o = blockIdx.x;
  int chunk = blockIdx.y;
  int lane = threadIdx.x;     // = c
  float acc[9];
  #pragma unroll
  for (int q = 0; q < 9; q++) acc[q] = 0.f;
  for (int rr = 0; rr < 16; rr++){
    int R = chunk*16 + rr;    // 0..1983
    int b = R / HP;
    int i = R % HP;
    // phase 1: p = r^2 into LDS (lanes 62,63 -> 0)
    float p = 0.f;
    if (lane < 62){
      int pos = R*62 + lane;
      float yv = y[(((size_t)b*On + o)*HP + i)*WP + lane];
      float r = __expf(yv - mbuf[pos]) * invdbuf[pos];
      p = r*r;
    }
    __syncthreads();
    pl[lane] = p;
    __syncthreads();
    const float* xrow = x + (((size_t)b*Cn + lane)*Hn + i)*Wn;
    for (int jj = 0; jj < 56; jj += 8){
      float4 p0 = *(const float4*)&pl[jj];
      float4 p1 = *(const float4*)&pl[jj+4];
      float pv[8] = {p0.x,p0.y,p0.z,p0.w,p1.x,p1.y,p1.z,p1.w};
      #pragma unroll
      for (int kh = 0; kh < 3; kh++){
        const float* xr = xrow + kh*Wn + jj;
        float4 a0 = *(const float4*)(xr);
        float4 a1 = *(const float4*)(xr + 4);
        float4 a2 = *(const float4*)(xr + 8);
        float xv[12] = {a0.x,a0.y,a0.z,a0.w,a1.x,a1.y,a1.z,a1.w,a2.x,a2.y,a2.z,a2.w};
        #pragma unroll
        for (int kw = 0; kw < 3; kw++){
          #pragma unroll
          for (int dj = 0; dj < 8; dj++) acc[kh*3+kw] += pv[dj]*xv[dj+kw];
        }
      }
    }
    { // tail jj = 56 (positions 56..63; 62,63 have p=0)
      float4 p0 = *(const float4*)&pl[56];
      float4 p1 = *(const float4*)&pl[60];
      float pv[8] = {p0.x,p0.y,p0.z,p0.w,p1.x,p1.y,p1.z,p1.w};
      #pragma unroll
      for (int kh = 0; kh < 3; kh++){
        const float* xr = xrow + kh*Wn + 56;
        float4 a0 = *(const float4*)(xr);
        float4 a1 = *(const float4*)(xr + 4);
        float xv[10] = {a0.x,a0.y,a0.z,a0.w,a1.x,a1.y,a1.z,a1.w,0.f,0.f};
        #pragma unroll
        for (int kw = 0; kw < 3; kw++){
          #pragma unroll
          for (int dj = 0; dj < 8; dj++) acc[kh*3+kw] += pv[dj]*xv[dj+kw];
        }
      }
    }
  }
  float* Gr = G + o*CKn + lane*9;
  #pragma unroll
  for (int q = 0; q < 9; q++) atomicAdd(&Gr[q], acc[q]);
}

__global__ __launch_bounds__(576) void k_final(const float* __restrict__ w, const float* __restrict__ G,
                                               const float* __restrict__ S1, const float* __restrict__ S2,
                                               float* __restrict__ dw){
  int o = blockIdx.x; int k = threadIdx.x;
  float s1 = S1[o]; if (s1 == 0.f) s1 = 1.f;
  dw[o*CKn + k] = (G[o*CKn + k] - S2[o]*w[o*CKn + k]) / s1;
}

extern "C" void kernel_launch(void* const* d_in, const int* in_sizes, int n_in,
                              void* d_out, int out_size, void* d_ws, size_t ws_size,
                              hipStream_t stream){
  const float* x    = (const float*)d_in[0];
  const float* w    = (const float*)d_in[1];
  const float* bias = (const float*)d_in[2];
  float* y  = (float*)d_out;
  float* dw = (float*)d_out + Y_ELEMS;
  float* ws = (float*)d_ws;
  float* wn   = ws;
  float* S1   = ws + 73728;
  float* S2   = ws + 73856;
  float* G    = ws + 73984;
  float* mbuf = ws + 147712;
  float* invd = ws + 270720;

  k_norm <<<dim3(On),        dim3(256), 0, stream>>>(w, wn, S1, S2, G);
  k_conv <<<dim3(Bn*On, 4),  dim3(256), 0, stream>>>(x, wn, bias, y);
  k_soft <<<dim3(Bn, 16),    dim3(256), 0, stream>>>(y, mbuf, invd, S1, S2);
  k_delta<<<dim3(On, NROWS/16), dim3(64), 0, stream>>>(x, y, mbuf, invd, G);
  k_final<<<dim3(On),        dim3(CKn), 0, stream>>>(w, G, S1, S2, dw);
}

// Round 2
// 2027.358 us; speedup vs baseline: 3.1284x; 3.1284x over previous
//
#include <hip/hip_runtime.h>

#define Bn 32
#define Cn 64
#define Hn 64
#define Wn 64
#define On 128
#define HP 62
#define WP 62
#define CKn 576
#define Ln (HP*WP)          // 3844
#define NPOS (Bn*Ln)        // 123008
#define NROWS (Bn*HP)       // 1984
#define Y_ELEMS (Bn*On*Ln)  // 15745024

// ws layout (floats):
// wn   : [0,      73728)
// S1   : [73728,  73856)
// S2   : [73856,  73984)
// G    : [73984,  147712)
// m    : [147712, 270720)
// invd : [270720, 393728)

__global__ __launch_bounds__(256) void k_norm(const float* __restrict__ w, float* __restrict__ wn,
                                              float* __restrict__ S1, float* __restrict__ S2,
                                              float* __restrict__ G){
  int o = blockIdx.x; int t = threadIdx.x;
  for (int k = t; k < CKn; k += 256) G[o*CKn + k] = 0.f;
  if (t == 0){ S1[o] = 0.f; S2[o] = 0.f; }
  float s = 0.f;
  for (int k = t; k < CKn; k += 256){ float v = w[o*CKn + k]; s += v*v; }
  #pragma unroll
  for (int off = 32; off; off >>= 1) s += __shfl_down(s, off);
  __shared__ float red[4]; __shared__ float sh_inv;
  if ((t & 63) == 0) red[t >> 6] = s;
  __syncthreads();
  if (t == 0){
    float tot = red[0] + red[1] + red[2] + red[3];
    float nrm = sqrtf(tot);
    sh_inv = (nrm == 0.f) ? 1.f : 1.f/nrm;
  }
  __syncthreads();
  float inv = sh_inv;
  for (int k = t; k < CKn; k += 256) wn[o*CKn + k] = w[o*CKn + k]*inv;
}

// conv: block = 256 thr: 16 rows x 16 j-groups (4 outputs each). grid (B*O, 4)
__global__ __launch_bounds__(256) void k_conv(const float* __restrict__ x, const float* __restrict__ wn,
                                              const float* __restrict__ bias, float* __restrict__ y){
  int bo = blockIdx.x;
  int b = bo >> 7, o = bo & 127;
  int t = threadIdx.x;
  int jg = t & 15;
  int ir = t >> 4;
  int i = blockIdx.y*16 + ir;
  int j0 = jg*4;
  int i_ld = i < 62 ? i : 61;
  int c2 = (j0 + 4 <= 60) ? (j0 + 4) : 56;
  const float* xb_base = x + (size_t)b*Cn*Hn*Wn;
  const float* wrow = wn + o*CKn;
  float acc0=0.f, acc1=0.f, acc2=0.f, acc3=0.f;
  for (int c = 0; c < Cn; c++){
    const float* xc = xb_base + (size_t)c*Hn*Wn + (size_t)i_ld*Wn;
    #pragma unroll
    for (int kh = 0; kh < 3; kh++){
      const float* xr = xc + kh*Wn;
      float4 a  = *(const float4*)(xr + j0);
      float4 bq = *(const float4*)(xr + c2);
      float w0 = wrow[c*9 + kh*3 + 0];
      float w1 = wrow[c*9 + kh*3 + 1];
      float w2 = wrow[c*9 + kh*3 + 2];
      acc0 += w0*a.x + w1*a.y + w2*a.z;
      acc1 += w0*a.y + w1*a.z + w2*a.w;
      acc2 += w0*a.z + w1*a.w + w2*bq.x;
      acc3 += w0*a.w + w1*bq.x + w2*bq.y;
    }
  }
  if (i < 62){
    float bv = bias[o];
    float* yp = y + (((size_t)b*On + o)*HP + i)*WP;
    yp[j0+0] = acc0 + bv;
    yp[j0+1] = acc1 + bv;
    if (j0+2 < 62) yp[j0+2] = acc2 + bv;
    if (j0+3 < 62) yp[j0+3] = acc3 + bv;
  }
}

// softmax stats: block = 4 rows x 64 lanes, grid (B, 16)
__global__ __launch_bounds__(256) void k_soft(const float* __restrict__ y, float* __restrict__ mbuf,
                                              float* __restrict__ invdbuf, float* __restrict__ S1,
                                              float* __restrict__ S2){
  __shared__ float s1loc[128], s2loc[128];
  int t = threadIdx.x;
  if (t < 128){ s1loc[t] = 0.f; s2loc[t] = 0.f; }
  __syncthreads();
  int b = blockIdx.x;
  int i = blockIdx.y*4 + (t >> 6);
  int j = t & 63;
  bool act = (i < 62) && (j < 62);
  const float* yp = y + (((size_t)b*On)*HP + (i < 62 ? i : 0))*WP + j;
  float mx = -3.0e38f;
  if (act){
    for (int o = 0; o < On; o++) mx = fmaxf(mx, yp[(size_t)o*Ln]);
  }
  float den = 0.f;
  if (act){
    for (int o = 0; o < On; o++) den += __expf(yp[(size_t)o*Ln] - mx);
  }
  float inv = act ? 1.f/den : 0.f;
  if (act){
    int pos = (b*HP + i)*WP + j;
    mbuf[pos] = mx; invdbuf[pos] = inv;
  }
  for (int o = 0; o < On; o++){
    float r = act ? __expf(yp[(size_t)o*Ln] - mx)*inv : 0.f;
    float s1v = r, s2v = r*r;
    #pragma unroll
    for (int off = 32; off; off >>= 1){ s1v += __shfl_down(s1v, off); s2v += __shfl_down(s2v, off); }
    if ((t & 63) == 0){ atomicAdd(&s1loc[o], s1v); atomicAdd(&s2loc[o], s2v); }
  }
  __syncthreads();
  if (t < 128){ atomicAdd(&S1[t], s1loc[t]); atomicAdd(&S2[t], s2loc[t]); }
}

// delta v2: block 256 = 4 waves. Covers 16 o's x 16-row strip. lane = c.
// x staged in 3-slot LDS ring, transposed [jw][c] (bank = c%32, 2-way = free).
// grid (8 o-tiles, 32 b * 4 strips)
__global__ __launch_bounds__(256) void k_delta(const float* __restrict__ x, const float* __restrict__ y,
                                              const float* __restrict__ mbuf, const float* __restrict__ invdbuf,
                                              float* __restrict__ G){
  __shared__ float planes[3][64][64];   // [slot][jw][c]
  __shared__ float plds[16][64];        // [o_local][j]
  int o0 = blockIdx.x * 16;
  int bs = blockIdx.y;
  int b = bs >> 2;
  int s = bs & 3;
  int i0 = s * 16;
  int nrows = (s == 3) ? 14 : 16;
  int t = threadIdx.x;
  int lane = t & 63;
  int w = t >> 6;
  int lc = t >> 2;              // loader: channel
  int lw0 = (t & 3) << 4;       // loader: width start
  const float* xb = x + (size_t)b*(Cn*Hn*Wn) + (size_t)lc*(Hn*Wn) + lw0;
  float acc[4][9];
  #pragma unroll
  for (int oi = 0; oi < 4; oi++)
    #pragma unroll
    for (int q = 0; q < 9; q++) acc[oi][q] = 0.f;

  // preload planes i0, i0+1
  #pragma unroll
  for (int pp = 0; pp < 2; pp++){
    int ih = i0 + pp;
    const float* src = xb + (size_t)ih*Wn;
    #pragma unroll
    for (int q = 0; q < 16; q++) planes[ih % 3][lw0 + q][lc] = src[q];
  }

  for (int ii = 0; ii < nrows; ii++){
    int i = i0 + ii;
    { // load plane i+2 (slot (i+2)%3 was last read in row i-1, protected by end-of-row sync)
      int ih = i + 2;
      const float* src = xb + (size_t)ih*Wn;
      #pragma unroll
      for (int q = 0; q < 16; q++) planes[ih % 3][lw0 + q][lc] = src[q];
    }
    // p = r^2 for this row's 16 o's (lanes 62,63 -> 0)
    int R = b*HP + i;
    #pragma unroll
    for (int oi = 0; oi < 4; oi++){
      int o = o0 + w*4 + oi;
      float p = 0.f;
      if (lane < WP){
        int pos = R*WP + lane;
        float yv = y[(((size_t)b*On + o)*HP + i)*WP + lane];
        float r = __expf(yv - mbuf[pos]) * invdbuf[pos];
        p = r*r;
      }
      plds[w*4 + oi][lane] = p;
    }
    __syncthreads();
    int c = lane;
    int s0 = i % 3, s1 = (i+1) % 3, s2g = (i+2) % 3;
    #pragma unroll 1
    for (int jj0 = 0; jj0 < 56; jj0 += 8){
      float xv[3][12];
      #pragma unroll
      for (int q = 0; q < 12; q++){
        xv[0][q] = planes[s0][jj0+q][c];
        xv[1][q] = planes[s1][jj0+q][c];
        xv[2][q] = planes[s2g][jj0+q][c];
      }
      #pragma unroll
      for (int oi = 0; oi < 4; oi++){
        float4 pa = *(const float4*)&plds[w*4+oi][jj0];
        float4 pb = *(const float4*)&plds[w*4+oi][jj0+4];
        float pv[8] = {pa.x,pa.y,pa.z,pa.w,pb.x,pb.y,pb.z,pb.w};
        #pragma unroll
        for (int kh = 0; kh < 3; kh++)
          #pragma unroll
          for (int kw = 0; kw < 3; kw++)
            #pragma unroll
            for (int dj = 0; dj < 8; dj++)
              acc[oi][kh*3+kw] += pv[dj]*xv[kh][dj+kw];
      }
    }
    { // tail jj0=56: jj 56..61 valid (p[62..63]=0), jw>=64 clamped to 0
      float xv[3][12];
      #pragma unroll
      for (int q = 0; q < 12; q++){
        bool ok = (56 + q) < 64;
        xv[0][q] = ok ? planes[s0][56+q][c] : 0.f;
        xv[1][q] = ok ? planes[s1][56+q][c] : 0.f;
        xv[2][q] = ok ? planes[s2g][56+q][c] : 0.f;
      }
      #pragma unroll
      for (int oi = 0; oi < 4; oi++){
        float4 pa = *(const float4*)&plds[w*4+oi][56];
        float4 pb = *(const float4*)&plds[w*4+oi][60];
        float pv[8] = {pa.x,pa.y,pa.z,pa.w,pb.x,pb.y,pb.z,pb.w};
        #pragma unroll
        for (int kh = 0; kh < 3; kh++)
          #pragma unroll
          for (int kw = 0; kw < 3; kw++)
            #pragma unroll
            for (int dj = 0; dj < 8; dj++)
              acc[oi][kh*3+kw] += pv[dj]*xv[kh][dj+kw];
      }
    }
    __syncthreads();
  }
  #pragma unroll
  for (int oi = 0; oi < 4; oi++){
    float* Gr = G + (size_t)(o0 + w*4 + oi)*CKn + lane*9;
    #pragma unroll
    for (int q = 0; q < 9; q++) atomicAdd(&Gr[q], acc[oi][q]);
  }
}

__global__ __launch_bounds__(576) void k_final(const float* __restrict__ w, const float* __restrict__ G,
                                               const float* __restrict__ S1, const float* __restrict__ S2,
                                               float* __restrict__ dw){
  int o = blockIdx.x; int k = threadIdx.x;
  float s1 = S1[o]; if (s1 == 0.f) s1 = 1.f;
  dw[o*CKn + k] = (G[o*CKn + k] - S2[o]*w[o*CKn + k]) / s1;
}

extern "C" void kernel_launch(void* const* d_in, const int* in_sizes, int n_in,
                              void* d_out, int out_size, void* d_ws, size_t ws_size,
                              hipStream_t stream){
  const float* x    = (const float*)d_in[0];
  const float* w    = (const float*)d_in[1];
  const float* bias = (const float*)d_in[2];
  float* y  = (float*)d_out;
  float* dw = (float*)d_out + Y_ELEMS;
  float* ws = (float*)d_ws;
  float* wn   = ws;
  float* S1   = ws + 73728;
  float* S2   = ws + 73856;
  float* G    = ws + 73984;
  float* mbuf = ws + 147712;
  float* invd = ws + 270720;

  k_norm <<<dim3(On),          dim3(256), 0, stream>>>(w, wn, S1, S2, G);
  k_conv <<<dim3(Bn*On, 4),    dim3(256), 0, stream>>>(x, wn, bias, y);
  k_soft <<<dim3(Bn, 16),      dim3(256), 0, stream>>>(y, mbuf, invd, S1, S2);
  k_delta<<<dim3(8, Bn*4),     dim3(256), 0, stream>>>(x, y, mbuf, invd, G);
  k_final<<<dim3(On),          dim3(CKn), 0, stream>>>(w, G, S1, S2, dw);
}

// Round 3
// 757.835 us; speedup vs baseline: 8.3690x; 2.6752x over previous
//
#include <hip/hip_runtime.h>

#define Bn 32
#define Cn 64
#define Hn 64
#define Wn 64
#define On 128
#define HP 62
#define WP 62
#define CKn 576
#define Ln (HP*WP)          // 3844
#define NPOS (Bn*Ln)        // 123008
#define NROWS (Bn*HP)       // 1984
#define Y_ELEMS (Bn*On*Ln)  // 15745024

typedef unsigned int uint32;
typedef unsigned short ushort16;
typedef __bf16 bf16x8 __attribute__((ext_vector_type(8)));
typedef float floatx4 __attribute__((ext_vector_type(4)));

static __device__ __forceinline__ uint32 bf16r(float f){
  uint32 u = __float_as_uint(f);
  return (u + 0x7FFFu + ((u >> 16) & 1u)) >> 16;
}

// ws layout (floats):
// (unused) : [0,      73728)
// S1   : [73728,  73856)
// S2   : [73856,  73984)
// G    : [73984,  147712)
// m    : [147712, 270720)
// invd : [270720, 393728)
// wnb (ushort): at float offset 393728, 73728 ushorts, layout [o][q*64+c]

__global__ __launch_bounds__(256) void k_norm(const float* __restrict__ w, ushort16* __restrict__ wnb,
                                              float* __restrict__ S1, float* __restrict__ S2,
                                              float* __restrict__ G){
  int o = blockIdx.x; int t = threadIdx.x;
  for (int k = t; k < CKn; k += 256) G[o*CKn + k] = 0.f;
  if (t == 0){ S1[o] = 0.f; S2[o] = 0.f; }
  float s = 0.f;
  for (int k = t; k < CKn; k += 256){ float v = w[o*CKn + k]; s += v*v; }
  #pragma unroll
  for (int off = 32; off; off >>= 1) s += __shfl_down(s, off);
  __shared__ float red[4]; __shared__ float sh_inv;
  if ((t & 63) == 0) red[t >> 6] = s;
  __syncthreads();
  if (t == 0){
    float tot = red[0] + red[1] + red[2] + red[3];
    float nrm = sqrtf(tot);
    sh_inv = (nrm == 0.f) ? 1.f : 1.f/nrm;
  }
  __syncthreads();
  float inv = sh_inv;
  for (int k = t; k < CKn; k += 256){
    float v = w[o*CKn + k] * inv;
    int c = k / 9;
    int q = k - c*9;
    wnb[o*CKn + q*64 + c] = (ushort16)bf16r(v);
  }
}

// MFMA implicit-GEMM conv. Block: M=124 (2 image rows) x N=128 (all o), K=576.
// K-order: k = (kh*3+kw)*64 + c. Slab [4 rows][64 w][68 c] bf16. B dbl-buffered.
__global__ __launch_bounds__(256, 3) void k_convm(const float* __restrict__ x,
                                                  const ushort16* __restrict__ wnb,
                                                  const float* __restrict__ bias,
                                                  float* __restrict__ y){
  __shared__ ushort16 slab[4*64*68];     // 34816 B
  __shared__ ushort16 Bl[2][128*36];     // 18432 B
  int t = threadIdx.x;
  int lane = t & 63;
  int wv = t >> 6;
  int mtile = blockIdx.x;                // 0..30
  int b = blockIdx.y;
  int i0 = mtile*2;

  // ---- stage slab: x[b][c][i0..i0+3][w] (f32) -> slab[r][w][c] (bf16)
  {
    int c0 = (t & 31)*2;
    int grp = t >> 5;                    // 0..7
    int r = grp >> 1;
    int w0 = (grp & 1)*32;
    const float* p0 = x + (((size_t)b*Cn + c0)*Hn + (i0 + r))*Wn + w0;
    const float* p1 = p0 + (size_t)Hn*Wn;
    #pragma unroll
    for (int ch = 0; ch < 4; ch++){
      float4 A0 = *(const float4*)(p0 + ch*8);
      float4 A1 = *(const float4*)(p0 + ch*8 + 4);
      float4 B0 = *(const float4*)(p1 + ch*8);
      float4 B1 = *(const float4*)(p1 + ch*8 + 4);
      float v0[8] = {A0.x,A0.y,A0.z,A0.w,A1.x,A1.y,A1.z,A1.w};
      float v1[8] = {B0.x,B0.y,B0.z,B0.w,B1.x,B1.y,B1.z,B1.w};
      #pragma unroll
      for (int qq = 0; qq < 8; qq++){
        int wloc = w0 + ch*8 + qq;
        *(uint32*)&slab[(r*64 + wloc)*68 + c0] = (bf16r(v1[qq]) << 16) | bf16r(v0[qq]);
      }
    }
  }

  // ---- B loader role
  int ob = t >> 1;                       // o 0..127
  int kh16 = (t & 1)*16;
  const ushort16* wrow = wnb + (size_t)ob*CKn + kh16;
  {
    uint4 bA = *(const uint4*)(wrow);
    uint4 bB = *(const uint4*)(wrow + 8);
    ushort16* dst = &Bl[0][ob*36 + kh16];
    ((uint2*)dst)[0] = make_uint2(bA.x, bA.y);
    ((uint2*)dst)[1] = make_uint2(bA.z, bA.w);
    ((uint2*)dst)[2] = make_uint2(bB.x, bB.y);
    ((uint2*)dst)[3] = make_uint2(bB.z, bB.w);
  }

  // ---- per-lane A addressing constants
  int quad8 = (lane >> 4) << 3;
  int iT[2], jT[2];
  #pragma unroll
  for (int mt = 0; mt < 2; mt++){
    int m = wv*32 + mt*16 + (lane & 15);
    int pos = m < 124 ? m : 123;
    int hi = pos >= 62;
    iT[mt] = hi;
    jT[mt] = pos - (hi ? 62 : 0);
  }

  floatx4 acc[2][8];
  #pragma unroll
  for (int mt = 0; mt < 2; mt++)
    #pragma unroll
    for (int nt = 0; nt < 8; nt++)
      acc[mt][nt] = (floatx4){0.f, 0.f, 0.f, 0.f};

  union U8 { uint2 u[2]; bf16x8 v; };

  for (int s = 0; s < 18; s++){
    uint4 nA, nB;
    if (s < 17){
      nA = *(const uint4*)(wrow + (s+1)*32);
      nB = *(const uint4*)(wrow + (s+1)*32 + 8);
    }
    __syncthreads();
    // A frags
    int k0 = s*32 + quad8;
    int q = k0 >> 6;
    int c0 = k0 & 63;
    int kh = (q*86) >> 8;
    int kw = q - kh*3;
    bf16x8 af[2];
    #pragma unroll
    for (int mt = 0; mt < 2; mt++){
      const ushort16* ap = &slab[((iT[mt] + kh)*64 + jT[mt] + kw)*68 + c0];
      U8 ua;
      ua.u[0] = *(const uint2*)(ap);
      ua.u[1] = *(const uint2*)(ap + 4);
      af[mt] = ua.v;
    }
    // B frags
    const ushort16* bbase = &Bl[s & 1][(lane & 15)*36 + quad8];
    bf16x8 bf[8];
    #pragma unroll
    for (int nt = 0; nt < 8; nt++){
      const ushort16* bp = bbase + nt*576;   // 16*36
      U8 ub;
      ub.u[0] = *(const uint2*)(bp);
      ub.u[1] = *(const uint2*)(bp + 4);
      bf[nt] = ub.v;
    }
    #pragma unroll
    for (int mt = 0; mt < 2; mt++)
      #pragma unroll
      for (int nt = 0; nt < 8; nt++)
        acc[mt][nt] = __builtin_amdgcn_mfma_f32_16x16x32_bf16(af[mt], bf[nt], acc[mt][nt], 0, 0, 0);
    if (s < 17){
      ushort16* dst = &Bl[(s+1) & 1][ob*36 + kh16];
      ((uint2*)dst)[0] = make_uint2(nA.x, nA.y);
      ((uint2*)dst)[1] = make_uint2(nA.z, nA.w);
      ((uint2*)dst)[2] = make_uint2(nB.x, nB.y);
      ((uint2*)dst)[3] = make_uint2(nB.z, nB.w);
    }
  }

  // ---- epilogue
  float bv[8];
  #pragma unroll
  for (int nt = 0; nt < 8; nt++) bv[nt] = bias[nt*16 + (lane & 15)];
  #pragma unroll
  for (int mt = 0; mt < 2; mt++){
    #pragma unroll
    for (int reg = 0; reg < 4; reg++){
      int m = wv*32 + mt*16 + (lane >> 4)*4 + reg;
      if (m < 124){
        int hi = m >= 62;
        int ii = i0 + hi;
        int jj = m - (hi ? 62 : 0);
        float* yp = y + (((size_t)b*On)*HP + ii)*WP + jj;
        #pragma unroll
        for (int nt = 0; nt < 8; nt++){
          int o = nt*16 + (lane & 15);
          yp[(size_t)o*Ln] = acc[mt][nt][reg] + bv[nt];
        }
      }
    }
  }
}

// softmax stats: block = 4 rows x 64 lanes, grid (B, 16)
__global__ __launch_bounds__(256) void k_soft(const float* __restrict__ y, float* __restrict__ mbuf,
                                              float* __restrict__ invdbuf, float* __restrict__ S1,
                                              float* __restrict__ S2){
  __shared__ float s1loc[128], s2loc[128];
  int t = threadIdx.x;
  if (t < 128){ s1loc[t] = 0.f; s2loc[t] = 0.f; }
  __syncthreads();
  int b = blockIdx.x;
  int i = blockIdx.y*4 + (t >> 6);
  int j = t & 63;
  bool act = (i < 62) && (j < 62);
  const float* yp = y + (((size_t)b*On)*HP + (i < 62 ? i : 0))*WP + j;
  float mx = -3.0e38f;
  if (act){
    for (int o = 0; o < On; o++) mx = fmaxf(mx, yp[(size_t)o*Ln]);
  }
  float den = 0.f;
  if (act){
    for (int o = 0; o < On; o++) den += __expf(yp[(size_t)o*Ln] - mx);
  }
  float inv = act ? 1.f/den : 0.f;
  if (act){
    int pos = (b*HP + i)*WP + j;
    mbuf[pos] = mx; invdbuf[pos] = inv;
  }
  for (int o = 0; o < On; o++){
    float r = act ? __expf(yp[(size_t)o*Ln] - mx)*inv : 0.f;
    float s1v = r, s2v = r*r;
    #pragma unroll
    for (int off = 32; off; off >>= 1){ s1v += __shfl_down(s1v, off); s2v += __shfl_down(s2v, off); }
    if ((t & 63) == 0){ atomicAdd(&s1loc[o], s1v); atomicAdd(&s2loc[o], s2v); }
  }
  __syncthreads();
  if (t < 128){ atomicAdd(&S1[t], s1loc[t]); atomicAdd(&S2[t], s2loc[t]); }
}

// delta: block 256 = 4 waves. 16 o's x 16-row strip. lane = c.
__global__ __launch_bounds__(256) void k_delta(const float* __restrict__ x, const float* __restrict__ y,
                                              const float* __restrict__ mbuf, const float* __restrict__ invdbuf,
                                              float* __restrict__ G){
  __shared__ float planes[3][64][64];   // [slot][jw][c]
  __shared__ float plds[16][64];        // [o_local][j]
  int o0 = blockIdx.x * 16;
  int bs = blockIdx.y;
  int b = bs >> 2;
  int s = bs & 3;
  int i0 = s * 16;
  int nrows = (s == 3) ? 14 : 16;
  int t = threadIdx.x;
  int lane = t & 63;
  int w = t >> 6;
  int lc = t >> 2;
  int lw0 = (t & 3) << 4;
  const float* xb = x + (size_t)b*(Cn*Hn*Wn) + (size_t)lc*(Hn*Wn) + lw0;
  float acc[4][9];
  #pragma unroll
  for (int oi = 0; oi < 4; oi++)
    #pragma unroll
    for (int q = 0; q < 9; q++) acc[oi][q] = 0.f;

  #pragma unroll
  for (int pp = 0; pp < 2; pp++){
    int ih = i0 + pp;
    const float* src = xb + (size_t)ih*Wn;
    #pragma unroll
    for (int q = 0; q < 16; q++) planes[ih % 3][lw0 + q][lc] = src[q];
  }

  for (int ii = 0; ii < nrows; ii++){
    int i = i0 + ii;
    {
      int ih = i + 2;
      const float* src = xb + (size_t)ih*Wn;
      #pragma unroll
      for (int q = 0; q < 16; q++) planes[ih % 3][lw0 + q][lc] = src[q];
    }
    int R = b*HP + i;
    #pragma unroll
    for (int oi = 0; oi < 4; oi++){
      int o = o0 + w*4 + oi;
      float p = 0.f;
      if (lane < WP){
        int pos = R*WP + lane;
        float yv = y[(((size_t)b*On + o)*HP + i)*WP + lane];
        float r = __expf(yv - mbuf[pos]) * invdbuf[pos];
        p = r*r;
      }
      plds[w*4 + oi][lane] = p;
    }
    __syncthreads();
    int c = lane;
    int s0 = i % 3, s1 = (i+1) % 3, s2g = (i+2) % 3;
    #pragma unroll 1
    for (int jj0 = 0; jj0 < 56; jj0 += 8){
      float xv[3][12];
      #pragma unroll
      for (int q = 0; q < 12; q++){
        xv[0][q] = planes[s0][jj0+q][c];
        xv[1][q] = planes[s1][jj0+q][c];
        xv[2][q] = planes[s2g][jj0+q][c];
      }
      #pragma unroll
      for (int oi = 0; oi < 4; oi++){
        float4 pa = *(const float4*)&plds[w*4+oi][jj0];
        float4 pb = *(const float4*)&plds[w*4+oi][jj0+4];
        float pv[8] = {pa.x,pa.y,pa.z,pa.w,pb.x,pb.y,pb.z,pb.w};
        #pragma unroll
        for (int kh = 0; kh < 3; kh++)
          #pragma unroll
          for (int kw = 0; kw < 3; kw++)
            #pragma unroll
            for (int dj = 0; dj < 8; dj++)
              acc[oi][kh*3+kw] += pv[dj]*xv[kh][dj+kw];
      }
    }
    {
      float xv[3][12];
      #pragma unroll
      for (int q = 0; q < 12; q++){
        bool ok = (56 + q) < 64;
        xv[0][q] = ok ? planes[s0][56+q][c] : 0.f;
        xv[1][q] = ok ? planes[s1][56+q][c] : 0.f;
        xv[2][q] = ok ? planes[s2g][56+q][c] : 0.f;
      }
      #pragma unroll
      for (int oi = 0; oi < 4; oi++){
        float4 pa = *(const float4*)&plds[w*4+oi][56];
        float4 pb = *(const float4*)&plds[w*4+oi][60];
        float pv[8] = {pa.x,pa.y,pa.z,pa.w,pb.x,pb.y,pb.z,pb.w};
        #pragma unroll
        for (int kh = 0; kh < 3; kh++)
          #pragma unroll
          for (int kw = 0; kw < 3; kw++)
            #pragma unroll
            for (int dj = 0; dj < 8; dj++)
              acc[oi][kh*3+kw] += pv[dj]*xv[kh][dj+kw];
      }
    }
    __syncthreads();
  }
  #pragma unroll
  for (int oi = 0; oi < 4; oi++){
    float* Gr = G + (size_t)(o0 + w*4 + oi)*CKn + lane*9;
    #pragma unroll
    for (int q = 0; q < 9; q++) atomicAdd(&Gr[q], acc[oi][q]);
  }
}

__global__ __launch_bounds__(576) void k_final(const float* __restrict__ w, const float* __restrict__ G,
                                               const float* __restrict__ S1, const float* __restrict__ S2,
                                               float* __restrict__ dw){
  int o = blockIdx.x; int k = threadIdx.x;
  float s1 = S1[o]; if (s1 == 0.f) s1 = 1.f;
  dw[o*CKn + k] = (G[o*CKn + k] - S2[o]*w[o*CKn + k]) / s1;
}

extern "C" void kernel_launch(void* const* d_in, const int* in_sizes, int n_in,
                              void* d_out, int out_size, void* d_ws, size_t ws_size,
                              hipStream_t stream){
  const float* x    = (const float*)d_in[0];
  const float* w    = (const float*)d_in[1];
  const float* bias = (const float*)d_in[2];
  float* y  = (float*)d_out;
  float* dw = (float*)d_out + Y_ELEMS;
  float* ws = (float*)d_ws;
  float* S1   = ws + 73728;
  float* S2   = ws + 73856;
  float* G    = ws + 73984;
  float* mbuf = ws + 147712;
  float* invd = ws + 270720;
  ushort16* wnb = (ushort16*)(ws + 393728);

  k_norm <<<dim3(On),           dim3(256), 0, stream>>>(w, wnb, S1, S2, G);
  k_convm<<<dim3(31, Bn),       dim3(256), 0, stream>>>(x, wnb, bias, y);
  k_soft <<<dim3(Bn, 16),       dim3(256), 0, stream>>>(y, mbuf, invd, S1, S2);
  k_delta<<<dim3(8, Bn*4),      dim3(256), 0, stream>>>(x, y, mbuf, invd, G);
  k_final<<<dim3(On),           dim3(CKn), 0, stream>>>(w, G, S1, S2, dw);
}

// Round 4
// 372.814 us; speedup vs baseline: 17.0121x; 2.0327x over previous
//
#include <hip/hip_runtime.h>

#define Bn 32
#define Cn 64
#define Hn 64
#define Wn 64
#define On 128
#define HP 62
#define WP 62
#define CKn 576
#define Ln (HP*WP)          // 3844
#define Y_ELEMS (Bn*On*Ln)  // 15745024

typedef unsigned int uint32;
typedef unsigned short ushort16;
typedef __bf16 bf16x8 __attribute__((ext_vector_type(8)));
typedef float floatx4 __attribute__((ext_vector_type(4)));

static __device__ __forceinline__ uint32 bf16r(float f){
  uint32 u = __float_as_uint(f);
  return (u + 0x7FFFu + ((u >> 16) & 1u)) >> 16;
}

// ---------------- new-path ws layout (floats) ----------------
// S1: 0..128, S2: 128..256, G: 256..73984
// wnb (ushort, 73728): float off 73984..110848
// xb  (ushort, 8388608): float off 110848..4305152 (+8 slack)
// pb  (ushort, 16252928): float off 4305160..12431624
#define NS1   0
#define NS2   128
#define NG    256
#define NWNB  73984
#define NXB   110848
#define NPB   4305160
#define WS_NEED ((size_t)49800000)

// ---------------- old-path ws layout (floats) ----------------
// S1 73728, S2 73856, G 73984, mbuf 147712, invd 270720, wnb 393728

__global__ __launch_bounds__(256) void k_norm(const float* __restrict__ w, ushort16* __restrict__ wnb,
                                              float* __restrict__ S1, float* __restrict__ S2,
                                              float* __restrict__ G){
  int o = blockIdx.x; int t = threadIdx.x;
  for (int k = t; k < CKn; k += 256) G[o*CKn + k] = 0.f;
  if (t == 0){ S1[o] = 0.f; S2[o] = 0.f; }
  float s = 0.f;
  for (int k = t; k < CKn; k += 256){ float v = w[o*CKn + k]; s += v*v; }
  #pragma unroll
  for (int off = 32; off; off >>= 1) s += __shfl_down(s, off);
  __shared__ float red[4]; __shared__ float sh_inv;
  if ((t & 63) == 0) red[t >> 6] = s;
  __syncthreads();
  if (t == 0){
    float tot = red[0] + red[1] + red[2] + red[3];
    float nrm = sqrtf(tot);
    sh_inv = (nrm == 0.f) ? 1.f : 1.f/nrm;
  }
  __syncthreads();
  float inv = sh_inv;
  for (int k = t; k < CKn; k += 256){
    float v = w[o*CKn + k] * inv;
    int c = k / 9;
    int q = k - c*9;
    wnb[o*CKn + q*64 + c] = (ushort16)bf16r(v);
  }
}

// x fp32 -> bf16, layout unchanged [b][c][h][w]
__global__ __launch_bounds__(256) void k_xb(const float* __restrict__ x, ushort16* __restrict__ xb){
  size_t idx = ((size_t)blockIdx.x*256 + threadIdx.x)*4;
  float4 v = *(const float4*)(x + idx);
  uint2 o;
  o.x = bf16r(v.x) | (bf16r(v.y) << 16);
  o.y = bf16r(v.z) | (bf16r(v.w) << 16);
  *(uint2*)(xb + idx) = o;
}

// MFMA implicit-GEMM conv (unchanged from round 3).
__global__ __launch_bounds__(256, 3) void k_convm(const float* __restrict__ x,
                                                  const ushort16* __restrict__ wnb,
                                                  const float* __restrict__ bias,
                                                  float* __restrict__ y){
  __shared__ ushort16 slab[4*64*68];
  __shared__ ushort16 Bl[2][128*36];
  int t = threadIdx.x;
  int lane = t & 63;
  int wv = t >> 6;
  int mtile = blockIdx.x;
  int b = blockIdx.y;
  int i0 = mtile*2;
  {
    int c0 = (t & 31)*2;
    int grp = t >> 5;
    int r = grp >> 1;
    int w0 = (grp & 1)*32;
    const float* p0 = x + (((size_t)b*Cn + c0)*Hn + (i0 + r))*Wn + w0;
    const float* p1 = p0 + (size_t)Hn*Wn;
    #pragma unroll
    for (int ch = 0; ch < 4; ch++){
      float4 A0 = *(const float4*)(p0 + ch*8);
      float4 A1 = *(const float4*)(p0 + ch*8 + 4);
      float4 B0 = *(const float4*)(p1 + ch*8);
      float4 B1 = *(const float4*)(p1 + ch*8 + 4);
      float v0[8] = {A0.x,A0.y,A0.z,A0.w,A1.x,A1.y,A1.z,A1.w};
      float v1[8] = {B0.x,B0.y,B0.z,B0.w,B1.x,B1.y,B1.z,B1.w};
      #pragma unroll
      for (int qq = 0; qq < 8; qq++){
        int wloc = w0 + ch*8 + qq;
        *(uint32*)&slab[(r*64 + wloc)*68 + c0] = (bf16r(v1[qq]) << 16) | bf16r(v0[qq]);
      }
    }
  }
  int ob = t >> 1;
  int kh16 = (t & 1)*16;
  const ushort16* wrow = wnb + (size_t)ob*CKn + kh16;
  {
    uint4 bA = *(const uint4*)(wrow);
    uint4 bB = *(const uint4*)(wrow + 8);
    ushort16* dst = &Bl[0][ob*36 + kh16];
    ((uint2*)dst)[0] = make_uint2(bA.x, bA.y);
    ((uint2*)dst)[1] = make_uint2(bA.z, bA.w);
    ((uint2*)dst)[2] = make_uint2(bB.x, bB.y);
    ((uint2*)dst)[3] = make_uint2(bB.z, bB.w);
  }
  int quad8 = (lane >> 4) << 3;
  int iT[2], jT[2];
  #pragma unroll
  for (int mt = 0; mt < 2; mt++){
    int m = wv*32 + mt*16 + (lane & 15);
    int pos = m < 124 ? m : 123;
    int hi = pos >= 62;
    iT[mt] = hi;
    jT[mt] = pos - (hi ? 62 : 0);
  }
  floatx4 acc[2][8];
  #pragma unroll
  for (int mt = 0; mt < 2; mt++)
    #pragma unroll
    for (int nt = 0; nt < 8; nt++)
      acc[mt][nt] = (floatx4){0.f, 0.f, 0.f, 0.f};
  union U8 { uint2 u[2]; bf16x8 v; };
  for (int s = 0; s < 18; s++){
    uint4 nA, nB;
    if (s < 17){
      nA = *(const uint4*)(wrow + (s+1)*32);
      nB = *(const uint4*)(wrow + (s+1)*32 + 8);
    }
    __syncthreads();
    int k0 = s*32 + quad8;
    int q = k0 >> 6;
    int c0 = k0 & 63;
    int kh = (q*86) >> 8;
    int kw = q - kh*3;
    bf16x8 af[2];
    #pragma unroll
    for (int mt = 0; mt < 2; mt++){
      const ushort16* ap = &slab[((iT[mt] + kh)*64 + jT[mt] + kw)*68 + c0];
      U8 ua;
      ua.u[0] = *(const uint2*)(ap);
      ua.u[1] = *(const uint2*)(ap + 4);
      af[mt] = ua.v;
    }
    const ushort16* bbase = &Bl[s & 1][(lane & 15)*36 + quad8];
    bf16x8 bf[8];
    #pragma unroll
    for (int nt = 0; nt < 8; nt++){
      const ushort16* bp = bbase + nt*576;
      U8 ub;
      ub.u[0] = *(const uint2*)(bp);
      ub.u[1] = *(const uint2*)(bp + 4);
      bf[nt] = ub.v;
    }
    #pragma unroll
    for (int mt = 0; mt < 2; mt++)
      #pragma unroll
      for (int nt = 0; nt < 8; nt++)
        acc[mt][nt] = __builtin_amdgcn_mfma_f32_16x16x32_bf16(af[mt], bf[nt], acc[mt][nt], 0, 0, 0);
    if (s < 17){
      ushort16* dst = &Bl[(s+1) & 1][ob*36 + kh16];
      ((uint2*)dst)[0] = make_uint2(nA.x, nA.y);
      ((uint2*)dst)[1] = make_uint2(nA.z, nA.w);
      ((uint2*)dst)[2] = make_uint2(nB.x, nB.y);
      ((uint2*)dst)[3] = make_uint2(nB.z, nB.w);
    }
  }
  float bv[8];
  #pragma unroll
  for (int nt = 0; nt < 8; nt++) bv[nt] = bias[nt*16 + (lane & 15)];
  #pragma unroll
  for (int mt = 0; mt < 2; mt++){
    #pragma unroll
    for (int reg = 0; reg < 4; reg++){
      int m = wv*32 + mt*16 + (lane >> 4)*4 + reg;
      if (m < 124){
        int hi = m >= 62;
        int ii = i0 + hi;
        int jj = m - (hi ? 62 : 0);
        float* yp = y + (((size_t)b*On)*HP + ii)*WP + jj;
        #pragma unroll
        for (int nt = 0; nt < 8; nt++){
          int o = nt*16 + (lane & 15);
          yp[(size_t)o*Ln] = acc[mt][nt][reg] + bv[nt];
        }
      }
    }
  }
}

// NEW fused softmax: online m/den (pass1) -> p=r^2 bf16 to pb + S1/S2 (pass2).
// grid (b, 8 strips of 8 rows), block 256.
__global__ __launch_bounds__(256) void k_softp(const float* __restrict__ y, ushort16* __restrict__ pb,
                                               float* __restrict__ S1, float* __restrict__ S2){
  __shared__ float ml[8][64], il[8][64];
  __shared__ float s1loc[128], s2loc[128];
  int b = blockIdx.x;
  int s = blockIdx.y;
  int i0 = s*8;
  int R = (s == 7) ? 6 : 8;
  int t = threadIdx.x;
  if (t < 128){ s1loc[t] = 0.f; s2loc[t] = 0.f; }
  int j = t & 63;
  int g = t >> 6;
  int je = j < WP ? j : (WP-1);
  for (int rr = g; rr < 8; rr += 4){
    if (rr < R){
      const float* yp = y + (((size_t)b*On)*HP + (i0+rr))*WP + je;
      float m = -3.0e38f, den = 0.f;
      for (int o = 0; o < On; o++){
        float v = yp[(size_t)o*Ln];
        float mn = fmaxf(m, v);
        den = den*__expf(m - mn) + __expf(v - mn);
        m = mn;
      }
      ml[rr][j] = m;
      il[rr][j] = 1.f/den;
    }
  }
  __syncthreads();
  for (int oc = 0; oc < 32; oc++){
    int o = oc*4 + g;
    float s1a = 0.f, s2a = 0.f;
    const float* yp = y + (((size_t)b*On + o)*HP + i0)*WP;
    ushort16* pp = pb + (((size_t)b*On + o)*HP + i0)*64;
    for (int rr = 0; rr < R; rr++){
      float r = 0.f;
      if (j < WP){
        float v = yp[rr*WP + j];
        r = __expf(v - ml[rr][j]) * il[rr][j];
      }
      pp[rr*64 + j] = (ushort16)bf16r(r*r);
      s1a += r;
      s2a += r*r;
    }
    #pragma unroll
    for (int off = 32; off; off >>= 1){ s1a += __shfl_down(s1a, off); s2a += __shfl_down(s2a, off); }
    if ((t & 63) == 0){ s1loc[o] += s1a; s2loc[o] += s2a; }
  }
  __syncthreads();
  if (t < 128){ atomicAdd(&S1[t], s1loc[t]); atomicAdd(&S2[t], s2loc[t]); }
}

// NEW split-K MFMA delta: G[o][q*64+c] += sum_pos p[pos][o]*x[b][c][i+kh][j+kw]
// grid (16 = 4 o-groups x 4 c-tiles, 32 b). Block 256 = 4 waves splitting K=124 ksteps.
__global__ __launch_bounds__(256) void k_deltam(const ushort16* __restrict__ xb,
                                                const ushort16* __restrict__ pb,
                                                float* __restrict__ G){
  __shared__ float Gl[32*144];
  int t = threadIdx.x;
  int lane = t & 63;
  int wv = t >> 6;
  int z = blockIdx.x;
  int b = blockIdx.y;
  int mg = z >> 2;
  int ntk = z & 3;
  for (int q = t; q < 32*144; q += 256) Gl[q] = 0.f;
  __syncthreads();
  int cl = lane & 15;
  int quad = lane >> 4;
  int quad8 = quad << 3;
  const ushort16* pA0 = pb + ((size_t)b*On + mg*32 + cl)*(HP*64);
  const ushort16* pA1 = pA0 + 16*(HP*64);
  const ushort16* xbase = xb + ((size_t)b*Cn + ntk*16 + cl)*(Hn*Wn);
  floatx4 acc[2][9];
  #pragma unroll
  for (int mt = 0; mt < 2; mt++)
    #pragma unroll
    for (int nt = 0; nt < 9; nt++)
      acc[mt][nt] = (floatx4){0.f, 0.f, 0.f, 0.f};
  union U16 { uint4 q; bf16x8 v; };
  for (int s = 0; s < 31; s++){
    int ks = wv*31 + s;
    int i = ks >> 1;
    int wb = ((ks & 1) << 5) + quad8;   // 0..56, 16B-aligned in bf16
    U16 a0, a1;
    a0.q = *(const uint4*)(pA0 + i*64 + wb);
    a1.q = *(const uint4*)(pA1 + i*64 + wb);
    #pragma unroll
    for (int kh = 0; kh < 3; kh++){
      const ushort16* xr = xbase + (i+kh)*Wn + wb;
      uint4 d = *(const uint4*)xr;
      uint32 d4 = *(const uint32*)(xr + 8);
      U16 f0, f1, f2;
      f0.q = d;
      f1.q = make_uint4((d.x>>16)|(d.y<<16), (d.y>>16)|(d.z<<16),
                        (d.z>>16)|(d.w<<16), (d.w>>16)|(d4<<16));
      f2.q = make_uint4(d.y, d.z, d.w, d4);
      acc[0][kh*3+0] = __builtin_amdgcn_mfma_f32_16x16x32_bf16(a0.v, f0.v, acc[0][kh*3+0], 0, 0, 0);
      acc[1][kh*3+0] = __builtin_amdgcn_mfma_f32_16x16x32_bf16(a1.v, f0.v, acc[1][kh*3+0], 0, 0, 0);
      acc[0][kh*3+1] = __builtin_amdgcn_mfma_f32_16x16x32_bf16(a0.v, f1.v, acc[0][kh*3+1], 0, 0, 0);
      acc[1][kh*3+1] = __builtin_amdgcn_mfma_f32_16x16x32_bf16(a1.v, f1.v, acc[1][kh*3+1], 0, 0, 0);
      acc[0][kh*3+2] = __builtin_amdgcn_mfma_f32_16x16x32_bf16(a0.v, f2.v, acc[0][kh*3+2], 0, 0, 0);
      acc[1][kh*3+2] = __builtin_amdgcn_mfma_f32_16x16x32_bf16(a1.v, f2.v, acc[1][kh*3+2], 0, 0, 0);
    }
  }
  // merge waves in LDS: D[row=o_local][col=ck_local], row = quad*4+reg, col n = cl
  #pragma unroll
  for (int mt = 0; mt < 2; mt++)
    #pragma unroll
    for (int nt = 0; nt < 9; nt++)
      #pragma unroll
      for (int reg = 0; reg < 4; reg++){
        int ol = mt*16 + quad*4 + reg;
        int col = nt*16 + cl;
        atomicAdd(&Gl[ol*144 + col], acc[mt][nt][reg]);
      }
  __syncthreads();
  for (int idx = t; idx < 32*144; idx += 256){
    int ol = idx / 144;
    int col = idx - ol*144;
    int q = col >> 4;
    int c = ntk*16 + (col & 15);
    atomicAdd(&G[(size_t)(mg*32 + ol)*CKn + q*64 + c], Gl[idx]);
  }
}

// final for new path: G layout [o][q*64+c] -> dw [o][c*9+q]
__global__ __launch_bounds__(576) void k_finalm(const float* __restrict__ w, const float* __restrict__ G,
                                                const float* __restrict__ S1, const float* __restrict__ S2,
                                                float* __restrict__ dw){
  int o = blockIdx.x; int k = threadIdx.x;
  int c = k / 9;
  int q = k - c*9;
  float s1 = S1[o]; if (s1 == 0.f) s1 = 1.f;
  dw[o*CKn + k] = (G[o*CKn + q*64 + c] - S2[o]*w[o*CKn + k]) / s1;
}

// ---------------- old fallback path (round-3 proven) ----------------
__global__ __launch_bounds__(256) void k_soft_old(const float* __restrict__ y, float* __restrict__ mbuf,
                                                  float* __restrict__ invdbuf, float* __restrict__ S1,
                                                  float* __restrict__ S2){
  __shared__ float s1loc[128], s2loc[128];
  int t = threadIdx.x;
  if (t < 128){ s1loc[t] = 0.f; s2loc[t] = 0.f; }
  __syncthreads();
  int b = blockIdx.x;
  int i = blockIdx.y*4 + (t >> 6);
  int j = t & 63;
  bool act = (i < 62) && (j < 62);
  const float* yp = y + (((size_t)b*On)*HP + (i < 62 ? i : 0))*WP + j;
  float mx = -3.0e38f;
  if (act){ for (int o = 0; o < On; o++) mx = fmaxf(mx, yp[(size_t)o*Ln]); }
  float den = 0.f;
  if (act){ for (int o = 0; o < On; o++) den += __expf(yp[(size_t)o*Ln] - mx); }
  float inv = act ? 1.f/den : 0.f;
  if (act){
    int pos = (b*HP + i)*WP + j;
    mbuf[pos] = mx; invdbuf[pos] = inv;
  }
  for (int o = 0; o < On; o++){
    float r = act ? __expf(yp[(size_t)o*Ln] - mx)*inv : 0.f;
    float s1v = r, s2v = r*r;
    #pragma unroll
    for (int off = 32; off; off >>= 1){ s1v += __shfl_down(s1v, off); s2v += __shfl_down(s2v, off); }
    if ((t & 63) == 0){ atomicAdd(&s1loc[o], s1v); atomicAdd(&s2loc[o], s2v); }
  }
  __syncthreads();
  if (t < 128){ atomicAdd(&S1[t], s1loc[t]); atomicAdd(&S2[t], s2loc[t]); }
}

__global__ __launch_bounds__(256) void k_delta_old(const float* __restrict__ x, const float* __restrict__ y,
                                                   const float* __restrict__ mbuf, const float* __restrict__ invdbuf,
                                                   float* __restrict__ G){
  __shared__ float planes[3][64][64];
  __shared__ float plds[16][64];
  int o0 = blockIdx.x * 16;
  int bs = blockIdx.y;
  int b = bs >> 2;
  int s = bs & 3;
  int i0 = s * 16;
  int nrows = (s == 3) ? 14 : 16;
  int t = threadIdx.x;
  int lane = t & 63;
  int w = t >> 6;
  int lc = t >> 2;
  int lw0 = (t & 3) << 4;
  const float* xb = x + (size_t)b*(Cn*Hn*Wn) + (size_t)lc*(Hn*Wn) + lw0;
  float acc[4][9];
  #pragma unroll
  for (int oi = 0; oi < 4; oi++)
    #pragma unroll
    for (int q = 0; q < 9; q++) acc[oi][q] = 0.f;
  #pragma unroll
  for (int pp = 0; pp < 2; pp++){
    int ih = i0 + pp;
    const float* src = xb + (size_t)ih*Wn;
    #pragma unroll
    for (int q = 0; q < 16; q++) planes[ih % 3][lw0 + q][lc] = src[q];
  }
  for (int ii = 0; ii < nrows; ii++){
    int i = i0 + ii;
    {
      int ih = i + 2;
      const float* src = xb + (size_t)ih*Wn;
      #pragma unroll
      for (int q = 0; q < 16; q++) planes[ih % 3][lw0 + q][lc] = src[q];
    }
    int R = b*HP + i;
    #pragma unroll
    for (int oi = 0; oi < 4; oi++){
      int o = o0 + w*4 + oi;
      float p = 0.f;
      if (lane < WP){
        int pos = R*WP + lane;
        float yv = y[(((size_t)b*On + o)*HP + i)*WP + lane];
        float r = __expf(yv - mbuf[pos]) * invdbuf[pos];
        p = r*r;
      }
      plds[w*4 + oi][lane] = p;
    }
    __syncthreads();
    int c = lane;
    int s0 = i % 3, s1 = (i+1) % 3, s2g = (i+2) % 3;
    #pragma unroll 1
    for (int jj0 = 0; jj0 < 56; jj0 += 8){
      float xv[3][12];
      #pragma unroll
      for (int q = 0; q < 12; q++){
        xv[0][q] = planes[s0][jj0+q][c];
        xv[1][q] = planes[s1][jj0+q][c];
        xv[2][q] = planes[s2g][jj0+q][c];
      }
      #pragma unroll
      for (int oi = 0; oi < 4; oi++){
        float4 pa = *(const float4*)&plds[w*4+oi][jj0];
        float4 pbq = *(const float4*)&plds[w*4+oi][jj0+4];
        float pv[8] = {pa.x,pa.y,pa.z,pa.w,pbq.x,pbq.y,pbq.z,pbq.w};
        #pragma unroll
        for (int kh = 0; kh < 3; kh++)
          #pragma unroll
          for (int kw = 0; kw < 3; kw++)
            #pragma unroll
            for (int dj = 0; dj < 8; dj++)
              acc[oi][kh*3+kw] += pv[dj]*xv[kh][dj+kw];
      }
    }
    {
      float xv[3][12];
      #pragma unroll
      for (int q = 0; q < 12; q++){
        bool ok = (56 + q) < 64;
        xv[0][q] = ok ? planes[s0][56+q][c] : 0.f;
        xv[1][q] = ok ? planes[s1][56+q][c] : 0.f;
        xv[2][q] = ok ? planes[s2g][56+q][c] : 0.f;
      }
      #pragma unroll
      for (int oi = 0; oi < 4; oi++){
        float4 pa = *(const float4*)&plds[w*4+oi][56];
        float4 pbq = *(const float4*)&plds[w*4+oi][60];
        float pv[8] = {pa.x,pa.y,pa.z,pa.w,pbq.x,pbq.y,pbq.z,pbq.w};
        #pragma unroll
        for (int kh = 0; kh < 3; kh++)
          #pragma unroll
          for (int kw = 0; kw < 3; kw++)
            #pragma unroll
            for (int dj = 0; dj < 8; dj++)
              acc[oi][kh*3+kw] += pv[dj]*xv[kh][dj+kw];
      }
    }
    __syncthreads();
  }
  #pragma unroll
  for (int oi = 0; oi < 4; oi++){
    float* Gr = G + (size_t)(o0 + w*4 + oi)*CKn + lane*9;
    #pragma unroll
    for (int q = 0; q < 9; q++) atomicAdd(&Gr[q], acc[oi][q]);
  }
}

__global__ __launch_bounds__(576) void k_final_old(const float* __restrict__ w, const float* __restrict__ G,
                                                   const float* __restrict__ S1, const float* __restrict__ S2,
                                                   float* __restrict__ dw){
  int o = blockIdx.x; int k = threadIdx.x;
  float s1 = S1[o]; if (s1 == 0.f) s1 = 1.f;
  dw[o*CKn + k] = (G[o*CKn + k] - S2[o]*w[o*CKn + k]) / s1;
}

extern "C" void kernel_launch(void* const* d_in, const int* in_sizes, int n_in,
                              void* d_out, int out_size, void* d_ws, size_t ws_size,
                              hipStream_t stream){
  const float* x    = (const float*)d_in[0];
  const float* w    = (const float*)d_in[1];
  const float* bias = (const float*)d_in[2];
  float* y  = (float*)d_out;
  float* dw = (float*)d_out + Y_ELEMS;
  float* ws = (float*)d_ws;

  if (ws_size >= WS_NEED){
    float* S1 = ws + NS1;
    float* S2 = ws + NS2;
    float* G  = ws + NG;
    ushort16* wnb = (ushort16*)(ws + NWNB);
    ushort16* xb  = (ushort16*)(ws + NXB);
    ushort16* pb  = (ushort16*)(ws + NPB);
    k_norm  <<<dim3(On),      dim3(256), 0, stream>>>(w, wnb, S1, S2, G);
    k_xb    <<<dim3(8192),    dim3(256), 0, stream>>>(x, xb);
    k_convm <<<dim3(31, Bn),  dim3(256), 0, stream>>>(x, wnb, bias, y);
    k_softp <<<dim3(Bn, 8),   dim3(256), 0, stream>>>(y, pb, S1, S2);
    k_deltam<<<dim3(16, Bn),  dim3(256), 0, stream>>>(xb, pb, G);
    k_finalm<<<dim3(On),      dim3(CKn), 0, stream>>>(w, G, S1, S2, dw);
  } else {
    float* S1   = ws + 73728;
    float* S2   = ws + 73856;
    float* G    = ws + 73984;
    float* mbuf = ws + 147712;
    float* invd = ws + 270720;
    ushort16* wnb = (ushort16*)(ws + 393728);
    k_norm     <<<dim3(On),      dim3(256), 0, stream>>>(w, wnb, S1, S2, G);
    k_convm    <<<dim3(31, Bn),  dim3(256), 0, stream>>>(x, wnb, bias, y);
    k_soft_old <<<dim3(Bn, 16),  dim3(256), 0, stream>>>(y, mbuf, invd, S1, S2);
    k_delta_old<<<dim3(8, Bn*4), dim3(256), 0, stream>>>(x, y, mbuf, invd, G);
    k_final_old<<<dim3(On),      dim3(CKn), 0, stream>>>(w, G, S1, S2, dw);
  }
}

// Round 5
// 315.813 us; speedup vs baseline: 20.0826x; 1.1805x over previous
//
#include <hip/hip_runtime.h>

#define Bn 32
#define Cn 64
#define Hn 64
#define Wn 64
#define On 128
#define HP 62
#define WP 62
#define CKn 576
#define Ln (HP*WP)          // 3844
#define Y_ELEMS (Bn*On*Ln)  // 15745024

typedef unsigned int uint32;
typedef unsigned short ushort16;
typedef __bf16 bf16x8 __attribute__((ext_vector_type(8)));
typedef float floatx4 __attribute__((ext_vector_type(4)));

static __device__ __forceinline__ uint32 bf16r(float f){
  uint32 u = __float_as_uint(f);
  return (u + 0x7FFFu + ((u >> 16) & 1u)) >> 16;
}

// ---------------- new-path ws layout (floats) ----------------
#define NS1   0
#define NS2   128
#define NG    256
#define NWNB  73984
#define NXB   110848
#define NPB   4305160
#define WS_NEED ((size_t)49800000)

__global__ __launch_bounds__(256) void k_norm(const float* __restrict__ w, ushort16* __restrict__ wnb,
                                              float* __restrict__ S1, float* __restrict__ S2,
                                              float* __restrict__ G){
  int o = blockIdx.x; int t = threadIdx.x;
  for (int k = t; k < CKn; k += 256) G[o*CKn + k] = 0.f;
  if (t == 0){ S1[o] = 0.f; S2[o] = 0.f; }
  float s = 0.f;
  for (int k = t; k < CKn; k += 256){ float v = w[o*CKn + k]; s += v*v; }
  #pragma unroll
  for (int off = 32; off; off >>= 1) s += __shfl_down(s, off);
  __shared__ float red[4]; __shared__ float sh_inv;
  if ((t & 63) == 0) red[t >> 6] = s;
  __syncthreads();
  if (t == 0){
    float tot = red[0] + red[1] + red[2] + red[3];
    float nrm = sqrtf(tot);
    sh_inv = (nrm == 0.f) ? 1.f : 1.f/nrm;
  }
  __syncthreads();
  float inv = sh_inv;
  for (int k = t; k < CKn; k += 256){
    float v = w[o*CKn + k] * inv;
    int c = k / 9;
    int q = k - c*9;
    wnb[o*CKn + q*64 + c] = (ushort16)bf16r(v);
  }
}

// x fp32 -> bf16, layout unchanged [b][c][h][w]
__global__ __launch_bounds__(256) void k_xb(const float* __restrict__ x, ushort16* __restrict__ xb){
  size_t idx = ((size_t)blockIdx.x*256 + threadIdx.x)*4;
  float4 v = *(const float4*)(x + idx);
  uint2 o;
  o.x = bf16r(v.x) | (bf16r(v.y) << 16);
  o.y = bf16r(v.z) | (bf16r(v.w) << 16);
  *(uint2*)(xb + idx) = o;
}

// MFMA implicit-GEMM conv (unchanged).
__global__ __launch_bounds__(256, 3) void k_convm(const float* __restrict__ x,
                                                  const ushort16* __restrict__ wnb,
                                                  const float* __restrict__ bias,
                                                  float* __restrict__ y){
  __shared__ ushort16 slab[4*64*68];
  __shared__ ushort16 Bl[2][128*36];
  int t = threadIdx.x;
  int lane = t & 63;
  int wv = t >> 6;
  int mtile = blockIdx.x;
  int b = blockIdx.y;
  int i0 = mtile*2;
  {
    int c0 = (t & 31)*2;
    int grp = t >> 5;
    int r = grp >> 1;
    int w0 = (grp & 1)*32;
    const float* p0 = x + (((size_t)b*Cn + c0)*Hn + (i0 + r))*Wn + w0;
    const float* p1 = p0 + (size_t)Hn*Wn;
    #pragma unroll
    for (int ch = 0; ch < 4; ch++){
      float4 A0 = *(const float4*)(p0 + ch*8);
      float4 A1 = *(const float4*)(p0 + ch*8 + 4);
      float4 B0 = *(const float4*)(p1 + ch*8);
      float4 B1 = *(const float4*)(p1 + ch*8 + 4);
      float v0[8] = {A0.x,A0.y,A0.z,A0.w,A1.x,A1.y,A1.z,A1.w};
      float v1[8] = {B0.x,B0.y,B0.z,B0.w,B1.x,B1.y,B1.z,B1.w};
      #pragma unroll
      for (int qq = 0; qq < 8; qq++){
        int wloc = w0 + ch*8 + qq;
        *(uint32*)&slab[(r*64 + wloc)*68 + c0] = (bf16r(v1[qq]) << 16) | bf16r(v0[qq]);
      }
    }
  }
  int ob = t >> 1;
  int kh16 = (t & 1)*16;
  const ushort16* wrow = wnb + (size_t)ob*CKn + kh16;
  {
    uint4 bA = *(const uint4*)(wrow);
    uint4 bB = *(const uint4*)(wrow + 8);
    ushort16* dst = &Bl[0][ob*36 + kh16];
    ((uint2*)dst)[0] = make_uint2(bA.x, bA.y);
    ((uint2*)dst)[1] = make_uint2(bA.z, bA.w);
    ((uint2*)dst)[2] = make_uint2(bB.x, bB.y);
    ((uint2*)dst)[3] = make_uint2(bB.z, bB.w);
  }
  int quad8 = (lane >> 4) << 3;
  int iT[2], jT[2];
  #pragma unroll
  for (int mt = 0; mt < 2; mt++){
    int m = wv*32 + mt*16 + (lane & 15);
    int pos = m < 124 ? m : 123;
    int hi = pos >= 62;
    iT[mt] = hi;
    jT[mt] = pos - (hi ? 62 : 0);
  }
  floatx4 acc[2][8];
  #pragma unroll
  for (int mt = 0; mt < 2; mt++)
    #pragma unroll
    for (int nt = 0; nt < 8; nt++)
      acc[mt][nt] = (floatx4){0.f, 0.f, 0.f, 0.f};
  union U8 { uint2 u[2]; bf16x8 v; };
  for (int s = 0; s < 18; s++){
    uint4 nA, nB;
    if (s < 17){
      nA = *(const uint4*)(wrow + (s+1)*32);
      nB = *(const uint4*)(wrow + (s+1)*32 + 8);
    }
    __syncthreads();
    int k0 = s*32 + quad8;
    int q = k0 >> 6;
    int c0 = k0 & 63;
    int kh = (q*86) >> 8;
    int kw = q - kh*3;
    bf16x8 af[2];
    #pragma unroll
    for (int mt = 0; mt < 2; mt++){
      const ushort16* ap = &slab[((iT[mt] + kh)*64 + jT[mt] + kw)*68 + c0];
      U8 ua;
      ua.u[0] = *(const uint2*)(ap);
      ua.u[1] = *(const uint2*)(ap + 4);
      af[mt] = ua.v;
    }
    const ushort16* bbase = &Bl[s & 1][(lane & 15)*36 + quad8];
    bf16x8 bf[8];
    #pragma unroll
    for (int nt = 0; nt < 8; nt++){
      const ushort16* bp = bbase + nt*576;
      U8 ub;
      ub.u[0] = *(const uint2*)(bp);
      ub.u[1] = *(const uint2*)(bp + 4);
      bf[nt] = ub.v;
    }
    #pragma unroll
    for (int mt = 0; mt < 2; mt++)
      #pragma unroll
      for (int nt = 0; nt < 8; nt++)
        acc[mt][nt] = __builtin_amdgcn_mfma_f32_16x16x32_bf16(af[mt], bf[nt], acc[mt][nt], 0, 0, 0);
    if (s < 17){
      ushort16* dst = &Bl[(s+1) & 1][ob*36 + kh16];
      ((uint2*)dst)[0] = make_uint2(nA.x, nA.y);
      ((uint2*)dst)[1] = make_uint2(nA.z, nA.w);
      ((uint2*)dst)[2] = make_uint2(nB.x, nB.y);
      ((uint2*)dst)[3] = make_uint2(nB.z, nB.w);
    }
  }
  float bv[8];
  #pragma unroll
  for (int nt = 0; nt < 8; nt++) bv[nt] = bias[nt*16 + (lane & 15)];
  #pragma unroll
  for (int mt = 0; mt < 2; mt++){
    #pragma unroll
    for (int reg = 0; reg < 4; reg++){
      int m = wv*32 + mt*16 + (lane >> 4)*4 + reg;
      if (m < 124){
        int hi = m >= 62;
        int ii = i0 + hi;
        int jj = m - (hi ? 62 : 0);
        float* yp = y + (((size_t)b*On)*HP + ii)*WP + jj;
        #pragma unroll
        for (int nt = 0; nt < 8; nt++){
          int o = nt*16 + (lane & 15);
          yp[(size_t)o*Ln] = acc[mt][nt][reg] + bv[nt];
        }
      }
    }
  }
}

// softmax v2: grid (b, 31 strips of 2 rows), block 256 = (og 0..3) x (j 0..63).
// pass1: online m/den over 32 o's per thread; 4-way LDS merge.
// pass2: p=r^2 bf16 coalesced writes; wave-reduce S1/S2 per o.
__global__ __launch_bounds__(256) void k_softp(const float* __restrict__ y, ushort16* __restrict__ pb,
                                               float* __restrict__ S1, float* __restrict__ S2){
  __shared__ float mpart[2][256], dpart[2][256];
  __shared__ float s1loc[128], s2loc[128];
  int b = blockIdx.x;
  int s = blockIdx.y;          // 0..30
  int i0 = s*2;
  int t = threadIdx.x;
  int j = t & 63;
  int og = t >> 6;
  if (t < 128){ s1loc[t] = 0.f; s2loc[t] = 0.f; }
  int je = j < WP ? j : (WP-1);
  const float* yb = y + ((size_t)b*On)*Ln + (size_t)i0*WP + je;
  // pass 1
  float m0 = -3.0e38f, m1 = -3.0e38f, d0 = 0.f, d1 = 0.f;
  for (int oi = 0; oi < 32; oi++){
    int o = og*32 + oi;
    const float* yp = yb + (size_t)o*Ln;
    float v0 = yp[0];
    float v1 = yp[WP];
    float n0 = fmaxf(m0, v0);
    d0 = d0*__expf(m0 - n0) + __expf(v0 - n0);
    m0 = n0;
    float n1 = fmaxf(m1, v1);
    d1 = d1*__expf(m1 - n1) + __expf(v1 - n1);
    m1 = n1;
  }
  mpart[0][t] = m0; dpart[0][t] = d0;
  mpart[1][t] = m1; dpart[1][t] = d1;
  __syncthreads();
  float mc[2], ic[2];
  #pragma unroll
  for (int r = 0; r < 2; r++){
    float ma = mpart[r][j],      mb = mpart[r][64+j];
    float mcc = mpart[r][128+j], md = mpart[r][192+j];
    float mm = fmaxf(fmaxf(ma, mb), fmaxf(mcc, md));
    float dd = dpart[r][j]*__expf(ma-mm) + dpart[r][64+j]*__expf(mb-mm)
             + dpart[r][128+j]*__expf(mcc-mm) + dpart[r][192+j]*__expf(md-mm);
    mc[r] = mm; ic[r] = 1.f/dd;
  }
  // pass 2
  bool act = j < WP;
  for (int oi = 0; oi < 32; oi++){
    int o = og*32 + oi;
    const float* yp = yb + (size_t)o*Ln;
    float r0 = 0.f, r1 = 0.f;
    if (act){
      r0 = __expf(yp[0] - mc[0]) * ic[0];
      r1 = __expf(yp[WP] - mc[1]) * ic[1];
    }
    float p0 = r0*r0, p1 = r1*r1;
    ushort16* pp = pb + (((size_t)b*On + o)*HP + i0)*64 + j;
    pp[0]  = (ushort16)bf16r(p0);
    pp[64] = (ushort16)bf16r(p1);
    float s1v = r0 + r1, s2v = p0 + p1;
    #pragma unroll
    for (int off = 32; off; off >>= 1){ s1v += __shfl_down(s1v, off); s2v += __shfl_down(s2v, off); }
    if (j == 0){ s1loc[o] += s1v; s2loc[o] += s2v; }   // single writer per o per block
  }
  __syncthreads();
  if (t < 128){ atomicAdd(&S1[t], s1loc[t]); atomicAdd(&S2[t], s2loc[t]); }
}

// split-K MFMA delta (unchanged)
__global__ __launch_bounds__(256) void k_deltam(const ushort16* __restrict__ xb,
                                                const ushort16* __restrict__ pb,
                                                float* __restrict__ G){
  __shared__ float Gl[32*144];
  int t = threadIdx.x;
  int lane = t & 63;
  int wv = t >> 6;
  int z = blockIdx.x;
  int b = blockIdx.y;
  int mg = z >> 2;
  int ntk = z & 3;
  for (int q = t; q < 32*144; q += 256) Gl[q] = 0.f;
  __syncthreads();
  int cl = lane & 15;
  int quad = lane >> 4;
  int quad8 = quad << 3;
  const ushort16* pA0 = pb + ((size_t)b*On + mg*32 + cl)*(HP*64);
  const ushort16* pA1 = pA0 + 16*(HP*64);
  const ushort16* xbase = xb + ((size_t)b*Cn + ntk*16 + cl)*(Hn*Wn);
  floatx4 acc[2][9];
  #pragma unroll
  for (int mt = 0; mt < 2; mt++)
    #pragma unroll
    for (int nt = 0; nt < 9; nt++)
      acc[mt][nt] = (floatx4){0.f, 0.f, 0.f, 0.f};
  union U16 { uint4 q; bf16x8 v; };
  for (int s = 0; s < 31; s++){
    int ks = wv*31 + s;
    int i = ks >> 1;
    int wb = ((ks & 1) << 5) + quad8;
    U16 a0, a1;
    a0.q = *(const uint4*)(pA0 + i*64 + wb);
    a1.q = *(const uint4*)(pA1 + i*64 + wb);
    #pragma unroll
    for (int kh = 0; kh < 3; kh++){
      const ushort16* xr = xbase + (i+kh)*Wn + wb;
      uint4 d = *(const uint4*)xr;
      uint32 d4 = *(const uint32*)(xr + 8);
      U16 f0, f1, f2;
      f0.q = d;
      f1.q = make_uint4((d.x>>16)|(d.y<<16), (d.y>>16)|(d.z<<16),
                        (d.z>>16)|(d.w<<16), (d.w>>16)|(d4<<16));
      f2.q = make_uint4(d.y, d.z, d.w, d4);
      acc[0][kh*3+0] = __builtin_amdgcn_mfma_f32_16x16x32_bf16(a0.v, f0.v, acc[0][kh*3+0], 0, 0, 0);
      acc[1][kh*3+0] = __builtin_amdgcn_mfma_f32_16x16x32_bf16(a1.v, f0.v, acc[1][kh*3+0], 0, 0, 0);
      acc[0][kh*3+1] = __builtin_amdgcn_mfma_f32_16x16x32_bf16(a0.v, f1.v, acc[0][kh*3+1], 0, 0, 0);
      acc[1][kh*3+1] = __builtin_amdgcn_mfma_f32_16x16x32_bf16(a1.v, f1.v, acc[1][kh*3+1], 0, 0, 0);
      acc[0][kh*3+2] = __builtin_amdgcn_mfma_f32_16x16x32_bf16(a0.v, f2.v, acc[0][kh*3+2], 0, 0, 0);
      acc[1][kh*3+2] = __builtin_amdgcn_mfma_f32_16x16x32_bf16(a1.v, f2.v, acc[1][kh*3+2], 0, 0, 0);
    }
  }
  #pragma unroll
  for (int mt = 0; mt < 2; mt++)
    #pragma unroll
    for (int nt = 0; nt < 9; nt++)
      #pragma unroll
      for (int reg = 0; reg < 4; reg++){
        int ol = mt*16 + quad*4 + reg;
        int col = nt*16 + cl;
        atomicAdd(&Gl[ol*144 + col], acc[mt][nt][reg]);
      }
  __syncthreads();
  for (int idx = t; idx < 32*144; idx += 256){
    int ol = idx / 144;
    int col = idx - ol*144;
    int q = col >> 4;
    int c = ntk*16 + (col & 15);
    atomicAdd(&G[(size_t)(mg*32 + ol)*CKn + q*64 + c], Gl[idx]);
  }
}

__global__ __launch_bounds__(576) void k_finalm(const float* __restrict__ w, const float* __restrict__ G,
                                                const float* __restrict__ S1, const float* __restrict__ S2,
                                                float* __restrict__ dw){
  int o = blockIdx.x; int k = threadIdx.x;
  int c = k / 9;
  int q = k - c*9;
  float s1 = S1[o]; if (s1 == 0.f) s1 = 1.f;
  dw[o*CKn + k] = (G[o*CKn + q*64 + c] - S2[o]*w[o*CKn + k]) / s1;
}

// ---------------- old fallback path ----------------
__global__ __launch_bounds__(256) void k_soft_old(const float* __restrict__ y, float* __restrict__ mbuf,
                                                  float* __restrict__ invdbuf, float* __restrict__ S1,
                                                  float* __restrict__ S2){
  __shared__ float s1loc[128], s2loc[128];
  int t = threadIdx.x;
  if (t < 128){ s1loc[t] = 0.f; s2loc[t] = 0.f; }
  __syncthreads();
  int b = blockIdx.x;
  int i = blockIdx.y*4 + (t >> 6);
  int j = t & 63;
  bool act = (i < 62) && (j < 62);
  const float* yp = y + (((size_t)b*On)*HP + (i < 62 ? i : 0))*WP + j;
  float mx = -3.0e38f;
  if (act){ for (int o = 0; o < On; o++) mx = fmaxf(mx, yp[(size_t)o*Ln]); }
  float den = 0.f;
  if (act){ for (int o = 0; o < On; o++) den += __expf(yp[(size_t)o*Ln] - mx); }
  float inv = act ? 1.f/den : 0.f;
  if (act){
    int pos = (b*HP + i)*WP + j;
    mbuf[pos] = mx; invdbuf[pos] = inv;
  }
  for (int o = 0; o < On; o++){
    float r = act ? __expf(yp[(size_t)o*Ln] - mx)*inv : 0.f;
    float s1v = r, s2v = r*r;
    #pragma unroll
    for (int off = 32; off; off >>= 1){ s1v += __shfl_down(s1v, off); s2v += __shfl_down(s2v, off); }
    if ((t & 63) == 0){ atomicAdd(&s1loc[o], s1v); atomicAdd(&s2loc[o], s2v); }
  }
  __syncthreads();
  if (t < 128){ atomicAdd(&S1[t], s1loc[t]); atomicAdd(&S2[t], s2loc[t]); }
}

__global__ __launch_bounds__(256) void k_delta_old(const float* __restrict__ x, const float* __restrict__ y,
                                                   const float* __restrict__ mbuf, const float* __restrict__ invdbuf,
                                                   float* __restrict__ G){
  __shared__ float planes[3][64][64];
  __shared__ float plds[16][64];
  int o0 = blockIdx.x * 16;
  int bs = blockIdx.y;
  int b = bs >> 2;
  int s = bs & 3;
  int i0 = s * 16;
  int nrows = (s == 3) ? 14 : 16;
  int t = threadIdx.x;
  int lane = t & 63;
  int w = t >> 6;
  int lc = t >> 2;
  int lw0 = (t & 3) << 4;
  const float* xb = x + (size_t)b*(Cn*Hn*Wn) + (size_t)lc*(Hn*Wn) + lw0;
  float acc[4][9];
  #pragma unroll
  for (int oi = 0; oi < 4; oi++)
    #pragma unroll
    for (int q = 0; q < 9; q++) acc[oi][q] = 0.f;
  #pragma unroll
  for (int pp = 0; pp < 2; pp++){
    int ih = i0 + pp;
    const float* src = xb + (size_t)ih*Wn;
    #pragma unroll
    for (int q = 0; q < 16; q++) planes[ih % 3][lw0 + q][lc] = src[q];
  }
  for (int ii = 0; ii < nrows; ii++){
    int i = i0 + ii;
    {
      int ih = i + 2;
      const float* src = xb + (size_t)ih*Wn;
      #pragma unroll
      for (int q = 0; q < 16; q++) planes[ih % 3][lw0 + q][lc] = src[q];
    }
    int R = b*HP + i;
    #pragma unroll
    for (int oi = 0; oi < 4; oi++){
      int o = o0 + w*4 + oi;
      float p = 0.f;
      if (lane < WP){
        int pos = R*WP + lane;
        float yv = y[(((size_t)b*On + o)*HP + i)*WP + lane];
        float r = __expf(yv - mbuf[pos]) * invdbuf[pos];
        p = r*r;
      }
      plds[w*4 + oi][lane] = p;
    }
    __syncthreads();
    int c = lane;
    int s0 = i % 3, s1 = (i+1) % 3, s2g = (i+2) % 3;
    #pragma unroll 1
    for (int jj0 = 0; jj0 < 56; jj0 += 8){
      float xv[3][12];
      #pragma unroll
      for (int q = 0; q < 12; q++){
        xv[0][q] = planes[s0][jj0+q][c];
        xv[1][q] = planes[s1][jj0+q][c];
        xv[2][q] = planes[s2g][jj0+q][c];
      }
      #pragma unroll
      for (int oi = 0; oi < 4; oi++){
        float4 pa = *(const float4*)&plds[w*4+oi][jj0];
        float4 pbq = *(const float4*)&plds[w*4+oi][jj0+4];
        float pv[8] = {pa.x,pa.y,pa.z,pa.w,pbq.x,pbq.y,pbq.z,pbq.w};
        #pragma unroll
        for (int kh = 0; kh < 3; kh++)
          #pragma unroll
          for (int kw = 0; kw < 3; kw++)
            #pragma unroll
            for (int dj = 0; dj < 8; dj++)
              acc[oi][kh*3+kw] += pv[dj]*xv[kh][dj+kw];
      }
    }
    {
      float xv[3][12];
      #pragma unroll
      for (int q = 0; q < 12; q++){
        bool ok = (56 + q) < 64;
        xv[0][q] = ok ? planes[s0][56+q][c] : 0.f;
        xv[1][q] = ok ? planes[s1][56+q][c] : 0.f;
        xv[2][q] = ok ? planes[s2g][56+q][c] : 0.f;
      }
      #pragma unroll
      for (int oi = 0; oi < 4; oi++){
        float4 pa = *(const float4*)&plds[w*4+oi][56];
        float4 pbq = *(const float4*)&plds[w*4+oi][60];
        float pv[8] = {pa.x,pa.y,pa.z,pa.w,pbq.x,pbq.y,pbq.z,pbq.w};
        #pragma unroll
        for (int kh = 0; kh < 3; kh++)
          #pragma unroll
          for (int kw = 0; kw < 3; kw++)
            #pragma unroll
            for (int dj = 0; dj < 8; dj++)
              acc[oi][kh*3+kw] += pv[dj]*xv[kh][dj+kw];
      }
    }
    __syncthreads();
  }
  #pragma unroll
  for (int oi = 0; oi < 4; oi++){
    float* Gr = G + (size_t)(o0 + w*4 + oi)*CKn + lane*9;
    #pragma unroll
    for (int q = 0; q < 9; q++) atomicAdd(&Gr[q], acc[oi][q]);
  }
}

__global__ __launch_bounds__(576) void k_final_old(const float* __restrict__ w, const float* __restrict__ G,
                                                   const float* __restrict__ S1, const float* __restrict__ S2,
                                                   float* __restrict__ dw){
  int o = blockIdx.x; int k = threadIdx.x;
  float s1 = S1[o]; if (s1 == 0.f) s1 = 1.f;
  dw[o*CKn + k] = (G[o*CKn + k] - S2[o]*w[o*CKn + k]) / s1;
}

extern "C" void kernel_launch(void* const* d_in, const int* in_sizes, int n_in,
                              void* d_out, int out_size, void* d_ws, size_t ws_size,
                              hipStream_t stream){
  const float* x    = (const float*)d_in[0];
  const float* w    = (const float*)d_in[1];
  const float* bias = (const float*)d_in[2];
  float* y  = (float*)d_out;
  float* dw = (float*)d_out + Y_ELEMS;
  float* ws = (float*)d_ws;

  if (ws_size >= WS_NEED){
    float* S1 = ws + NS1;
    float* S2 = ws + NS2;
    float* G  = ws + NG;
    ushort16* wnb = (ushort16*)(ws + NWNB);
    ushort16* xb  = (ushort16*)(ws + NXB);
    ushort16* pb  = (ushort16*)(ws + NPB);
    k_norm  <<<dim3(On),      dim3(256), 0, stream>>>(w, wnb, S1, S2, G);
    k_xb    <<<dim3(8192),    dim3(256), 0, stream>>>(x, xb);
    k_convm <<<dim3(31, Bn),  dim3(256), 0, stream>>>(x, wnb, bias, y);
    k_softp <<<dim3(Bn, 31),  dim3(256), 0, stream>>>(y, pb, S1, S2);
    k_deltam<<<dim3(16, Bn),  dim3(256), 0, stream>>>(xb, pb, G);
    k_finalm<<<dim3(On),      dim3(CKn), 0, stream>>>(w, G, S1, S2, dw);
  } else {
    float* S1   = ws + 73728;
    float* S2   = ws + 73856;
    float* G    = ws + 73984;
    float* mbuf = ws + 147712;
    float* invd = ws + 270720;
    ushort16* wnb = (ushort16*)(ws + 393728);
    k_norm     <<<dim3(On),      dim3(256), 0, stream>>>(w, wnb, S1, S2, G);
    k_convm    <<<dim3(31, Bn),  dim3(256), 0, stream>>>(x, wnb, bias, y);
    k_soft_old <<<dim3(Bn, 16),  dim3(256), 0, stream>>>(y, mbuf, invd, S1, S2);
    k_delta_old<<<dim3(8, Bn*4), dim3(256), 0, stream>>>(x, y, mbuf, invd, G);
    k_final_old<<<dim3(On),      dim3(CKn), 0, stream>>>(w, G, S1, S2, dw);
  }
}